// Round 4
// baseline (144.575 us; speedup 1.0000x reference)
//
#include <hip/hip_runtime.h>
#include <hip/hip_bf16.h>

// SelfAttentionLayer: B=64, N=1024, C=128, D=64
// R8: ONE isolated change vs R7: attn occupancy 2->4 waves/SIMD.
//   attn now 16 q-rows/wave (s-strip removed), grid 1024, lb(256,4)
//   => wave state ~110-125 VGPR (kf2 buffer dropped; next-kt K loads go
//   directly into kf after QK), under the 128-VGPR / 4-wave-per-SIMD cap.
//   R4 instruction ORDER preserved (R5 proved the schedule is fragile):
//   V-load -> QK(all strips) -> K-reload -> exp/pack -> PV.
// Theory: attn is latency-bound at 2 waves/SIMD (static ~190 VGPR); the
// per-kt serial chain (L2 load ~300cy, exp, LDS round-trip) has no TLP to
// hide under. Doubling resident waves halves exposed latency.
// qkv/wprep: unchanged from R7 (XCD-affine remap kept — neutral but sound).

#define Bsz 64
#define Nsz 1024
#define Csz 128
#define Dsz 64

typedef __attribute__((ext_vector_type(8))) short short8;
typedef __attribute__((ext_vector_type(4))) float f32x4;

__device__ __forceinline__ unsigned short f2bf(float f) {
    union { float f; unsigned u; } v; v.f = f;
    unsigned r = v.u + 0x7FFF + ((v.u >> 16) & 1);
    return (unsigned short)(r >> 16);
}
__device__ __forceinline__ float bf2f(unsigned short h) {
    union { unsigned u; float f; } v; v.u = ((unsigned)h) << 16;
    return v.f;
}
__device__ __forceinline__ unsigned pack_bf16rn(float lo, float hi) {
    unsigned ulo = __float_as_uint(lo) + 0x8000u;
    unsigned uhi = __float_as_uint(hi) + 0x8000u;
    return __builtin_amdgcn_perm(uhi, ulo, 0x07060302u);
}

#define SCq (0.125f * 1.44269504f)     // 1/sqrt(D) * log2(e) folded into qs
#define INV_SC (1.0f / (0.125f * 1.44269504f))

// ---------------- Kernel 0: weight prep -> B-frag layout bf16 ----------------
__global__ __launch_bounds__(256) void wprep_kernel(
    const float* __restrict__ Wq, const float* __restrict__ Wk,
    const float* __restrict__ Wv, unsigned short* __restrict__ wfrag)
{
    int t = blockIdx.x * 256 + threadIdx.x;   // 0..1023 = (dt,ksi,lane)
    int lane = t & 63, ksi = (t >> 6) & 3, dt = t >> 8;
    int l16 = lane & 15, quad = lane >> 4;
    int d = dt * 16 + l16;
    int c0 = ksi * 32 + quad * 8;
    short8 h8, l8, k8, v8;
    #pragma unroll
    for (int j = 0; j < 8; j++) {
        float w = Wq[(c0 + j) * Dsz + d];
        unsigned short h = f2bf(w);
        h8[j] = (short)h;
        l8[j] = (short)f2bf(w - bf2f(h));
        k8[j] = (short)f2bf(Wk[(c0 + j) * Dsz + d]);
        v8[j] = (short)f2bf(Wv[(c0 + j) * Dsz + d]);
    }
    int idx = (dt * 4 + ksi) * 64 + lane;
    ((short8*)wfrag)[0 * 1024 + idx] = h8;
    ((short8*)wfrag)[1 * 1024 + idx] = l8;
    ((short8*)wfrag)[2 * 1024 + idx] = k8;
    ((short8*)wfrag)[3 * 1024 + idx] = v8;
}

// ---------------- Kernel A: QKV projection via MFMA ----------------
// grid 1024 x 256; block = 64 rows; wave = d-tile dt.
// XCD-affine remap (bijective): blk -> (batch, tile) with batch%8 == blk%8.
__global__ __launch_bounds__(256) void qkv_kernel(
    const float* __restrict__ x, const unsigned short* __restrict__ wfrag,
    const float* __restrict__ bq, const float* __restrict__ bk,
    const float* __restrict__ bv,
    unsigned short* __restrict__ qs, unsigned short* __restrict__ ks2,
    unsigned short* __restrict__ vt2)
{
    __shared__ short xh[8192];   // [4 rt][4 ks][64 lane][8] A-frag layout
    __shared__ short xl[8192];
    const int t    = threadIdx.x;
    const int lane = t & 63;
    const int l16  = lane & 15, quad = lane >> 4;
    const int dt   = t >> 6;
    const int blk = blockIdx.x;
    const int r8  = blk & 7;
    const int m   = blk >> 3;                  // 0..127
    const int bat = r8 + 8 * (m >> 4);         // 0..63
    const int til = m & 15;                    // 0..15
    const long rowbase = ((long)bat * 16 + til) * 64;
    const int d = dt * 16 + l16;

    // weight B-frags: 16 coalesced b128 loads (L2-hot wfrag)
    short8 wqh[4], wql[4], wkf[4], wvf[4];
    #pragma unroll
    for (int ksi = 0; ksi < 4; ksi++) {
        int idx = (dt * 4 + ksi) * 64 + lane;
        wqh[ksi] = ((const short8*)wfrag)[0 * 1024 + idx];
        wql[ksi] = ((const short8*)wfrag)[1 * 1024 + idx];
        wkf[ksi] = ((const short8*)wfrag)[2 * 1024 + idx];
        wvf[ksi] = ((const short8*)wfrag)[3 * 1024 + idx];
    }

    // stage x -> bf16 hi/lo in A-frag layout
    {
        const int row = t & 63;
        const float* xrow = x + (rowbase + row) * Csz;
        #pragma unroll
        for (int p = 0; p < 4; p++) {
            int cb = (t >> 6) + p * 4;
            float4 a = *(const float4*)(xrow + cb * 8);
            float4 bb = *(const float4*)(xrow + cb * 8 + 4);
            float f[8] = {a.x, a.y, a.z, a.w, bb.x, bb.y, bb.z, bb.w};
            short8 hi, lo;
            #pragma unroll
            for (int i = 0; i < 8; i++) {
                unsigned short h = f2bf(f[i]);
                hi[i] = (short)h;
                lo[i] = (short)f2bf(f[i] - bf2f(h));
            }
            int unit = ((row >> 4) * 4 + (cb >> 2)) * 64 + ((row & 15) | ((cb & 3) << 4));
            *(short8*)&xh[unit * 8] = hi;
            *(short8*)&xl[unit * 8] = lo;
        }
    }
    __syncthreads();

    f32x4 aq[4], ak[4], av[4];
    #pragma unroll
    for (int i = 0; i < 4; i++) {
        aq[i] = (f32x4){0.f, 0.f, 0.f, 0.f};
        ak[i] = (f32x4){0.f, 0.f, 0.f, 0.f};
        av[i] = (f32x4){0.f, 0.f, 0.f, 0.f};
    }
    #pragma unroll
    for (int ksi = 0; ksi < 4; ksi++) {
        #pragma unroll
        for (int rt = 0; rt < 4; rt++) {
            short8 ah = *(const short8*)&xh[((rt * 4 + ksi) * 64 + lane) * 8];
            short8 al = *(const short8*)&xl[((rt * 4 + ksi) * 64 + lane) * 8];
            aq[rt] = __builtin_amdgcn_mfma_f32_16x16x32_bf16(ah, wqh[ksi], aq[rt], 0, 0, 0);
            aq[rt] = __builtin_amdgcn_mfma_f32_16x16x32_bf16(al, wqh[ksi], aq[rt], 0, 0, 0);
            aq[rt] = __builtin_amdgcn_mfma_f32_16x16x32_bf16(ah, wql[ksi], aq[rt], 0, 0, 0);
            ak[rt] = __builtin_amdgcn_mfma_f32_16x16x32_bf16(ah, wkf[ksi], ak[rt], 0, 0, 0);
            av[rt] = __builtin_amdgcn_mfma_f32_16x16x32_bf16(ah, wvf[ksi], av[rt], 0, 0, 0);
        }
    }

    // ---- epilogue ----
    const float bqd = bq[d], bkd = bk[d], bvd = bv[d];
    const long b  = rowbase >> 10;
    const int  kt = (int)((rowbase >> 6) & 15);

    // K frag-scatter constants: value(n,d) -> frag (kb=rt, half, lane=quadk*16+quad*4+r, j)
    const int half  = dt >> 1;
    const int quadk = ((dt & 1) << 1) | (l16 >> 3);
    const int jk    = l16 & 7;
    unsigned short* kbase = ks2 + ((((long)(b * 16 + kt) * 4) * 2 + half) * 64) * 8;

    float vv[4][4];   // [r][rt]
    #pragma unroll
    for (int rt = 0; rt < 4; rt++) {
        #pragma unroll
        for (int r = 0; r < 4; r++) {
            long n = rowbase + rt * 16 + quad * 4 + r;
            float q = fmaxf(aq[rt][r] + bqd, 0.f);
            float k = fmaxf(ak[rt][r] + bkd, 0.f);
            vv[r][rt] = fmaxf(av[rt][r] + bvd, 0.f);
            qs[n * Dsz + d] = f2bf(q * SCq);
            kbase[((long)rt * 2 * 64 + quadk * 16 + quad * 4 + r) * 8 + jk] = f2bf(k);
        }
    }
    // V frag-major stores: 2 x b128. lane slot = quadp*16 + l16, shorts j=r*4+rt (mod 8)
    const int ck = quad >> 1;
    const int quadp = (quad & 1) * 2;
    long vidx = (((long)(b * 16 + kt) * 4 + dt) * 2 + ck) * 64 + quadp * 16 + l16;
    uint4 o0 = make_uint4(pack_bf16rn(vv[0][0], vv[0][1]), pack_bf16rn(vv[0][2], vv[0][3]),
                          pack_bf16rn(vv[1][0], vv[1][1]), pack_bf16rn(vv[1][2], vv[1][3]));
    uint4 o1 = make_uint4(pack_bf16rn(vv[2][0], vv[2][1]), pack_bf16rn(vv[2][2], vv[2][3]),
                          pack_bf16rn(vv[3][0], vv[3][1]), pack_bf16rn(vv[3][2], vv[3][3]));
    ((uint4*)vt2)[vidx]      = o0;
    ((uint4*)vt2)[vidx + 16] = o1;
}

// ---------------- Kernel B: barrier-free flash attention ----------------
// grid 1024: b = blk&63 (XCD L2 affinity), qh = blk>>6 (0..15). 4 waves x
// 16 q rows. lb(256,4): <=128 VGPR -> 4 blocks/CU = 4 waves/SIMD.
// R4 schedule order per kt: V-load -> QK -> K-reload(kt+1) -> exp -> PV.
__global__ __launch_bounds__(256, 4) void attn_kernel(
    const unsigned short* __restrict__ qs,
    const unsigned short* __restrict__ ks2,
    const unsigned short* __restrict__ vt2,
    float* __restrict__ out)
{
    __shared__ short Pl[4][16][72];    // per-wave P (C->A layout round-trip)

    const int t    = threadIdx.x;
    const int wave = t >> 6;
    const int lane = t & 63;
    const int l16  = lane & 15;
    const int quad = lane >> 4;
    const int b    = blockIdx.x & 63;
    const int qh   = blockIdx.x >> 6;
    const int qbase = qh * 64 + wave * 16;

    const short8* ks8 = (const short8*)ks2 + (long)b * (16 * 4 * 2 * 64);
    const short8* vt8 = (const short8*)vt2 + (long)b * (16 * 4 * 2 * 64);

    // Q A-frags (one 16-row strip)
    short8 aq[2];
    {
        const unsigned short* qp = qs + ((long)b * Nsz + qbase + l16) * Dsz + quad * 8;
        aq[0] = *(const short8*)(qp);
        aq[1] = *(const short8*)(qp + 32);
    }

    f32x4 O[4];
    float lsum[4];
    #pragma unroll
    for (int i = 0; i < 4; i++) { O[i] = (f32x4){0.f,0.f,0.f,0.f}; lsum[i] = 0.f; }

    // preload K-frags for kt=0: frag idx (kb*2+half)*64 + lane
    short8 kf[4][2];
    #pragma unroll
    for (int kb = 0; kb < 4; kb++) {
        kf[kb][0] = ks8[(kb * 2 + 0) * 64 + lane];
        kf[kb][1] = ks8[(kb * 2 + 1) * 64 + lane];
    }

    for (int kt = 0; kt < 16; kt++) {
        // V frags for this kt — issued first, consumed at PV
        short8 bvf[2][4];
        #pragma unroll
        for (int cb = 0; cb < 4; cb++) {
            bvf[0][cb] = vt8[((long)kt * 8 + cb * 2 + 0) * 64 + lane];
            bvf[1][cb] = vt8[((long)kt * 8 + cb * 2 + 1) * 64 + lane];
        }

        // S = q K^T
        f32x4 sc[4];
        #pragma unroll
        for (int kb = 0; kb < 4; kb++) {
            f32x4 z = (f32x4){0.f, 0.f, 0.f, 0.f};
            z = __builtin_amdgcn_mfma_f32_16x16x32_bf16(aq[0], kf[kb][0], z, 0, 0, 0);
            z = __builtin_amdgcn_mfma_f32_16x16x32_bf16(aq[1], kf[kb][1], z, 0, 0, 0);
            sc[kb] = z;
        }

        // reload K-frags for kt+1 directly into kf (QK already issued; no
        // separate kf2 buffer -> 32 VGPR saved; flies under exp+PV)
        {
            int ktn = (kt + 1) & 15;
            #pragma unroll
            for (int kb = 0; kb < 4; kb++) {
                kf[kb][0] = ks8[((long)ktn * 8 + kb * 2 + 0) * 64 + lane];
                kf[kb][1] = ks8[((long)ktn * 8 + kb * 2 + 1) * 64 + lane];
            }
        }

        // P = 2^S, pi-packed b64 into per-wave Pl
        #pragma unroll
        for (int r = 0; r < 4; r++) {
            float p0 = __builtin_amdgcn_exp2f(sc[0][r]);
            float p1 = __builtin_amdgcn_exp2f(sc[1][r]);
            float p2 = __builtin_amdgcn_exp2f(sc[2][r]);
            float p3 = __builtin_amdgcn_exp2f(sc[3][r]);
            lsum[r] += (p0 + p1) + (p2 + p3);
            *(uint2*)&Pl[wave][quad * 4 + r][l16 * 4] =
                make_uint2(pack_bf16rn(p0, p1), pack_bf16rn(p2, p3));
        }

        // O += P V (within-wave Pl read in A-layout; lgkmcnt only, no barrier)
        #pragma unroll
        for (int ck = 0; ck < 2; ck++) {
            short8 ap = *(const short8*)&Pl[wave][l16][ck * 32 + quad * 8];
            #pragma unroll
            for (int cb = 0; cb < 4; cb++) {
                O[cb] = __builtin_amdgcn_mfma_f32_16x16x32_bf16(ap, bvf[ck][cb], O[cb], 0, 0, 0);
            }
        }
    }

    // deferred row-sum reduction (lanes sharing a row: same quad, l16 0..15)
    #pragma unroll
    for (int r = 0; r < 4; r++)
        #pragma unroll
        for (int off = 1; off < 16; off <<= 1)
            lsum[r] += __shfl_xor(lsum[r], off);

    // epilogue: out = O/l + q (q from bf16 scaled copy)
    #pragma unroll
    for (int r = 0; r < 4; r++) {
        float rl = 1.0f / lsum[r];
        long nrow = (long)b * Nsz + qbase + quad * 4 + r;
        #pragma unroll
        for (int cb = 0; cb < 4; cb++) {
            int d = cb * 16 + l16;
            float qv = bf2f(qs[nrow * Dsz + d]) * INV_SC;
            out[nrow * Dsz + d] = O[cb][r] * rl + qv;
        }
    }
}

extern "C" void kernel_launch(void* const* d_in, const int* in_sizes, int n_in,
                              void* d_out, int out_size, void* d_ws, size_t ws_size,
                              hipStream_t stream) {
    const float* x  = (const float*)d_in[0];
    const float* Wq = (const float*)d_in[1];
    const float* bq = (const float*)d_in[2];
    const float* Wk = (const float*)d_in[3];
    const float* bk = (const float*)d_in[4];
    const float* Wv = (const float*)d_in[5];
    const float* bv = (const float*)d_in[6];
    float* out = (float*)d_out;

    char* ws = (char*)d_ws;
    unsigned short* qsc   = (unsigned short*)ws;                 // 8 MB bf16 q*SC, [n][d]
    unsigned short* ks2   = (unsigned short*)(ws + 0x1000000);   // 8 MB bf16 K frag-major
    unsigned short* vt2   = (unsigned short*)(ws + 0x2000000);   // 8 MB bf16 V^T frag-major
    unsigned short* wfrag = (unsigned short*)(ws + 0x3000000);   // 64 KB W frags

    wprep_kernel<<<dim3(4), dim3(256), 0, stream>>>(Wq, Wk, Wv, wfrag);
    qkv_kernel<<<dim3(1024), dim3(256), 0, stream>>>(
        x, wfrag, bq, bk, bv, qsc, ks2, vt2);
    attn_kernel<<<dim3(1024), dim3(256), 0, stream>>>(
        qsc, ks2, vt2, out);
}

// Round 5
// 123.618 us; speedup vs baseline: 1.1695x; 1.1695x over previous
//
#include <hip/hip_runtime.h>
#include <hip/hip_bf16.h>

// SelfAttentionLayer: B=64, N=1024, C=128, D=64
// R9: counters from R8 (MfmaUtil 12%, VALUBusy 20%, Occ 33%) => attn is
// L2-bandwidth/latency-bound because ALL 4 waves of a block load IDENTICAL
// K/V frags (4x redundant L2 traffic).
//  (1) attn: LDS-stage K/V once per block via global_load_lds (16B wide),
//      double-buffered; each wave stages 4 of 16 frags; waves read frags
//      from LDS (b128, conflict-free linear layout). L2 traffic /4; stage
//      of kt+1 flies under compute of kt; syncthreads drain per kt.
//      Per-wave compute body = R7's proven 32-q/wave schedule.
//  (2) qkv: K frag-scatter (16 scattered 2B stores/thread) replaced by
//      row-major coalesced K store (same shape as qs store). attn gathers
//      the B-frag from row-major K via per-lane global_load_lds source
//      addresses: lane(l16,quad) <- K[kb*16+l16][half*32+quad*8..+7]
//      (derived by inverting the old scatter; same values, same rounding).
// vt2 stays frag-major (its stores were already packed b128).

#define Bsz 64
#define Nsz 1024
#define Csz 128
#define Dsz 64

typedef __attribute__((ext_vector_type(8))) short short8;
typedef __attribute__((ext_vector_type(4))) float f32x4;

__device__ __forceinline__ unsigned short f2bf(float f) {
    union { float f; unsigned u; } v; v.f = f;
    unsigned r = v.u + 0x7FFF + ((v.u >> 16) & 1);
    return (unsigned short)(r >> 16);
}
__device__ __forceinline__ float bf2f(unsigned short h) {
    union { unsigned u; float f; } v; v.u = ((unsigned)h) << 16;
    return v.f;
}
__device__ __forceinline__ unsigned pack_bf16rn(float lo, float hi) {
    unsigned ulo = __float_as_uint(lo) + 0x8000u;
    unsigned uhi = __float_as_uint(hi) + 0x8000u;
    return __builtin_amdgcn_perm(uhi, ulo, 0x07060302u);
}
// async global->LDS, 16B/lane. dst is wave-uniform frag base (HW adds lane*16);
// src is per-lane.
__device__ __forceinline__ void gload_lds16(const void* gsrc, void* ldst) {
    __builtin_amdgcn_global_load_lds(
        (const __attribute__((address_space(1))) void*)gsrc,
        (__attribute__((address_space(3))) void*)ldst,
        16, 0, 0);
}

#define SCq (0.125f * 1.44269504f)     // 1/sqrt(D) * log2(e) folded into qs
#define INV_SC (1.0f / (0.125f * 1.44269504f))

// ---------------- Kernel 0: weight prep -> B-frag layout bf16 ----------------
__global__ __launch_bounds__(256) void wprep_kernel(
    const float* __restrict__ Wq, const float* __restrict__ Wk,
    const float* __restrict__ Wv, unsigned short* __restrict__ wfrag)
{
    int t = blockIdx.x * 256 + threadIdx.x;   // 0..1023 = (dt,ksi,lane)
    int lane = t & 63, ksi = (t >> 6) & 3, dt = t >> 8;
    int l16 = lane & 15, quad = lane >> 4;
    int d = dt * 16 + l16;
    int c0 = ksi * 32 + quad * 8;
    short8 h8, l8, k8, v8;
    #pragma unroll
    for (int j = 0; j < 8; j++) {
        float w = Wq[(c0 + j) * Dsz + d];
        unsigned short h = f2bf(w);
        h8[j] = (short)h;
        l8[j] = (short)f2bf(w - bf2f(h));
        k8[j] = (short)f2bf(Wk[(c0 + j) * Dsz + d]);
        v8[j] = (short)f2bf(Wv[(c0 + j) * Dsz + d]);
    }
    int idx = (dt * 4 + ksi) * 64 + lane;
    ((short8*)wfrag)[0 * 1024 + idx] = h8;
    ((short8*)wfrag)[1 * 1024 + idx] = l8;
    ((short8*)wfrag)[2 * 1024 + idx] = k8;
    ((short8*)wfrag)[3 * 1024 + idx] = v8;
}

// ---------------- Kernel A: QKV projection via MFMA ----------------
// grid 1024 x 256; block = 64 rows; wave = d-tile dt.
// XCD-affine remap (bijective): blk -> (batch, tile) with batch%8 == blk%8.
__global__ __launch_bounds__(256) void qkv_kernel(
    const float* __restrict__ x, const unsigned short* __restrict__ wfrag,
    const float* __restrict__ bq, const float* __restrict__ bk,
    const float* __restrict__ bv,
    unsigned short* __restrict__ qs, unsigned short* __restrict__ ksr,
    unsigned short* __restrict__ vt2)
{
    __shared__ short xh[8192];   // [4 rt][4 ks][64 lane][8] A-frag layout
    __shared__ short xl[8192];
    const int t    = threadIdx.x;
    const int lane = t & 63;
    const int l16  = lane & 15, quad = lane >> 4;
    const int dt   = t >> 6;
    const int blk = blockIdx.x;
    const int r8  = blk & 7;
    const int m   = blk >> 3;                  // 0..127
    const int bat = r8 + 8 * (m >> 4);         // 0..63
    const int til = m & 15;                    // 0..15
    const long rowbase = ((long)bat * 16 + til) * 64;
    const int d = dt * 16 + l16;

    // weight B-frags: 16 coalesced b128 loads (L2-hot wfrag)
    short8 wqh[4], wql[4], wkf[4], wvf[4];
    #pragma unroll
    for (int ksi = 0; ksi < 4; ksi++) {
        int idx = (dt * 4 + ksi) * 64 + lane;
        wqh[ksi] = ((const short8*)wfrag)[0 * 1024 + idx];
        wql[ksi] = ((const short8*)wfrag)[1 * 1024 + idx];
        wkf[ksi] = ((const short8*)wfrag)[2 * 1024 + idx];
        wvf[ksi] = ((const short8*)wfrag)[3 * 1024 + idx];
    }

    // stage x -> bf16 hi/lo in A-frag layout
    {
        const int row = t & 63;
        const float* xrow = x + (rowbase + row) * Csz;
        #pragma unroll
        for (int p = 0; p < 4; p++) {
            int cb = (t >> 6) + p * 4;
            float4 a = *(const float4*)(xrow + cb * 8);
            float4 bb = *(const float4*)(xrow + cb * 8 + 4);
            float f[8] = {a.x, a.y, a.z, a.w, bb.x, bb.y, bb.z, bb.w};
            short8 hi, lo;
            #pragma unroll
            for (int i = 0; i < 8; i++) {
                unsigned short h = f2bf(f[i]);
                hi[i] = (short)h;
                lo[i] = (short)f2bf(f[i] - bf2f(h));
            }
            int unit = ((row >> 4) * 4 + (cb >> 2)) * 64 + ((row & 15) | ((cb & 3) << 4));
            *(short8*)&xh[unit * 8] = hi;
            *(short8*)&xl[unit * 8] = lo;
        }
    }
    __syncthreads();

    f32x4 aq[4], ak[4], av[4];
    #pragma unroll
    for (int i = 0; i < 4; i++) {
        aq[i] = (f32x4){0.f, 0.f, 0.f, 0.f};
        ak[i] = (f32x4){0.f, 0.f, 0.f, 0.f};
        av[i] = (f32x4){0.f, 0.f, 0.f, 0.f};
    }
    #pragma unroll
    for (int ksi = 0; ksi < 4; ksi++) {
        #pragma unroll
        for (int rt = 0; rt < 4; rt++) {
            short8 ah = *(const short8*)&xh[((rt * 4 + ksi) * 64 + lane) * 8];
            short8 al = *(const short8*)&xl[((rt * 4 + ksi) * 64 + lane) * 8];
            aq[rt] = __builtin_amdgcn_mfma_f32_16x16x32_bf16(ah, wqh[ksi], aq[rt], 0, 0, 0);
            aq[rt] = __builtin_amdgcn_mfma_f32_16x16x32_bf16(al, wqh[ksi], aq[rt], 0, 0, 0);
            aq[rt] = __builtin_amdgcn_mfma_f32_16x16x32_bf16(ah, wql[ksi], aq[rt], 0, 0, 0);
            ak[rt] = __builtin_amdgcn_mfma_f32_16x16x32_bf16(ah, wkf[ksi], ak[rt], 0, 0, 0);
            av[rt] = __builtin_amdgcn_mfma_f32_16x16x32_bf16(ah, wvf[ksi], av[rt], 0, 0, 0);
        }
    }

    // ---- epilogue ----
    const float bqd = bq[d], bkd = bk[d], bvd = bv[d];
    const long b  = rowbase >> 10;
    const int  kt = (int)((rowbase >> 6) & 15);

    float vv[4][4];   // [r][rt]
    #pragma unroll
    for (int rt = 0; rt < 4; rt++) {
        #pragma unroll
        for (int r = 0; r < 4; r++) {
            long n = rowbase + rt * 16 + quad * 4 + r;
            float q = fmaxf(aq[rt][r] + bqd, 0.f);
            float k = fmaxf(ak[rt][r] + bkd, 0.f);
            vv[r][rt] = fmaxf(av[rt][r] + bvd, 0.f);
            qs[n * Dsz + d]  = f2bf(q * SCq);
            ksr[n * Dsz + d] = f2bf(k);        // row-major coalesced (was frag-scatter)
        }
    }
    // V frag-major stores: 2 x b128. lane slot = quadp*16 + l16, shorts j=r*4+rt (mod 8)
    const int ck = quad >> 1;
    const int quadp = (quad & 1) * 2;
    long vidx = (((long)(b * 16 + kt) * 4 + dt) * 2 + ck) * 64 + quadp * 16 + l16;
    uint4 o0 = make_uint4(pack_bf16rn(vv[0][0], vv[0][1]), pack_bf16rn(vv[0][2], vv[0][3]),
                          pack_bf16rn(vv[1][0], vv[1][1]), pack_bf16rn(vv[1][2], vv[1][3]));
    uint4 o1 = make_uint4(pack_bf16rn(vv[2][0], vv[2][1]), pack_bf16rn(vv[2][2], vv[2][3]),
                          pack_bf16rn(vv[3][0], vv[3][1]), pack_bf16rn(vv[3][2], vv[3][3]));
    ((uint4*)vt2)[vidx]      = o0;
    ((uint4*)vt2)[vidx + 16] = o1;
}

// ---------------- Kernel B: LDS-staged flash attention ----------------
// grid 512: b = blk&63, qh = blk>>6. 4 waves x 32 q rows (R7 body).
// K/V frags staged once per block into double-buffered LDS via
// global_load_lds; each wave stages 4 of 16 frags; all waves read all
// frags from LDS => L2 K/V traffic /4.
__global__ __launch_bounds__(256, 2) void attn_kernel(
    const unsigned short* __restrict__ qs,
    const unsigned short* __restrict__ ksr,
    const unsigned short* __restrict__ vt2,
    float* __restrict__ out)
{
    __shared__ short KV[2][16][512];   // 2 bufs x 16 frags x 1KB (f<8: K, f>=8: V)
    __shared__ short Pl[4][32][72];    // per-wave P (C->A layout round-trip)

    const int t    = threadIdx.x;
    const int wave = t >> 6;
    const int lane = t & 63;
    const int l16  = lane & 15;
    const int quad = lane >> 4;
    const int b    = blockIdx.x & 63;
    const int qh   = blockIdx.x >> 6;
    const int qbase = qh * 128 + wave * 32;

    const char*   kbR = (const char*)(ksr + (long)b * Nsz * Dsz);  // 128B rows
    const short8* vt8 = (const short8*)vt2 + (long)b * (16 * 4 * 2 * 64);

    // stage frags for K-tile kt into KV[buf]:
    //   waves 0,1 -> K frags f=0..7 (kb=f>>1, half=f&1):
    //     lane(l16,quad) <- K[kt*64 + kb*16 + l16][half*32 + quad*8 ..+7]
    //   waves 2,3 -> V frags f=8..15 (contiguous frag-major copy)
    auto stage = [&](int buf, int kt) {
        if (wave < 2) {
            #pragma unroll
            for (int i = 0; i < 4; i++) {
                int f = wave * 4 + i;
                int kb = f >> 1, hf = f & 1;
                const char* src = kbR + ((long)kt * 64 + kb * 16 + l16) * 128
                                  + hf * 64 + quad * 16;
                gload_lds16(src, &KV[buf][f][0]);
            }
        } else {
            #pragma unroll
            for (int i = 0; i < 4; i++) {
                int f = (wave - 2) * 4 + i;
                const short8* src = vt8 + ((long)kt * 8 + f) * 64 + lane;
                gload_lds16(src, &KV[buf][8 + f][0]);
            }
        }
    };

    // Q A-frags
    short8 aq[2][2];
    #pragma unroll
    for (int s = 0; s < 2; s++) {
        const unsigned short* qp = qs + ((long)b * Nsz + qbase + s * 16 + l16) * Dsz + quad * 8;
        aq[s][0] = *(const short8*)(qp);
        aq[s][1] = *(const short8*)(qp + 32);
    }

    f32x4 O[2][4];
    float lsum[2][4];
    #pragma unroll
    for (int s = 0; s < 2; s++)
        #pragma unroll
        for (int i = 0; i < 4; i++) { O[s][i] = (f32x4){0.f,0.f,0.f,0.f}; lsum[s][i] = 0.f; }

    // prologue: stage kt=0 into buf 0
    stage(0, 0);
    __syncthreads();   // drains vmcnt -> KV[0] ready

    for (int kt = 0; kt < 16; kt++) {
        const int cur = kt & 1;
        // issue next tile's stage into the other buffer (flies under compute)
        if (kt < 15) stage(cur ^ 1, kt + 1);

        // K frags from LDS
        short8 kf[4][2];
        #pragma unroll
        for (int kb = 0; kb < 4; kb++) {
            kf[kb][0] = *(const short8*)&KV[cur][kb * 2 + 0][lane * 8];
            kf[kb][1] = *(const short8*)&KV[cur][kb * 2 + 1][lane * 8];
        }

        // S = q K^T per strip
        f32x4 sc[2][4];
        #pragma unroll
        for (int s = 0; s < 2; s++) {
            #pragma unroll
            for (int kb = 0; kb < 4; kb++) {
                f32x4 z = (f32x4){0.f, 0.f, 0.f, 0.f};
                z = __builtin_amdgcn_mfma_f32_16x16x32_bf16(aq[s][0], kf[kb][0], z, 0, 0, 0);
                z = __builtin_amdgcn_mfma_f32_16x16x32_bf16(aq[s][1], kf[kb][1], z, 0, 0, 0);
                sc[s][kb] = z;
            }
        }

        // V frags from LDS (issued before exp; consumed at PV)
        short8 bvf[2][4];
        #pragma unroll
        for (int cb = 0; cb < 4; cb++) {
            bvf[0][cb] = *(const short8*)&KV[cur][8 + cb * 2 + 0][lane * 8];
            bvf[1][cb] = *(const short8*)&KV[cur][8 + cb * 2 + 1][lane * 8];
        }

        // P = 2^S, pi-packed b64 into per-wave Pl
        #pragma unroll
        for (int s = 0; s < 2; s++) {
            #pragma unroll
            for (int r = 0; r < 4; r++) {
                float p0 = __builtin_amdgcn_exp2f(sc[s][0][r]);
                float p1 = __builtin_amdgcn_exp2f(sc[s][1][r]);
                float p2 = __builtin_amdgcn_exp2f(sc[s][2][r]);
                float p3 = __builtin_amdgcn_exp2f(sc[s][3][r]);
                lsum[s][r] += (p0 + p1) + (p2 + p3);
                *(uint2*)&Pl[wave][s * 16 + quad * 4 + r][l16 * 4] =
                    make_uint2(pack_bf16rn(p0, p1), pack_bf16rn(p2, p3));
            }
        }

        // O += P V (within-wave Pl read in A-layout; lgkmcnt only, no barrier)
        #pragma unroll
        for (int ck = 0; ck < 2; ck++) {
            #pragma unroll
            for (int s = 0; s < 2; s++) {
                short8 ap = *(const short8*)&Pl[wave][s * 16 + l16][ck * 32 + quad * 8];
                #pragma unroll
                for (int cb = 0; cb < 4; cb++) {
                    O[s][cb] = __builtin_amdgcn_mfma_f32_16x16x32_bf16(ap, bvf[ck][cb], O[s][cb], 0, 0, 0);
                }
            }
        }

        // all waves done with KV[cur]; next-tile stage (into cur^1) drained
        __syncthreads();
    }

    // deferred row-sum reduction (lanes sharing a row: same quad, l16 0..15)
    #pragma unroll
    for (int s = 0; s < 2; s++)
        #pragma unroll
        for (int r = 0; r < 4; r++)
            #pragma unroll
            for (int off = 1; off < 16; off <<= 1)
                lsum[s][r] += __shfl_xor(lsum[s][r], off);

    // epilogue: out = O/l + q (q from bf16 scaled copy)
    #pragma unroll
    for (int s = 0; s < 2; s++) {
        #pragma unroll
        for (int r = 0; r < 4; r++) {
            float rl = 1.0f / lsum[s][r];
            long nrow = (long)b * Nsz + qbase + s * 16 + quad * 4 + r;
            #pragma unroll
            for (int cb = 0; cb < 4; cb++) {
                int d = cb * 16 + l16;
                float qv = bf2f(qs[nrow * Dsz + d]) * INV_SC;
                out[nrow * Dsz + d] = O[s][cb][r] * rl + qv;
            }
        }
    }
}

extern "C" void kernel_launch(void* const* d_in, const int* in_sizes, int n_in,
                              void* d_out, int out_size, void* d_ws, size_t ws_size,
                              hipStream_t stream) {
    const float* x  = (const float*)d_in[0];
    const float* Wq = (const float*)d_in[1];
    const float* bq = (const float*)d_in[2];
    const float* Wk = (const float*)d_in[3];
    const float* bk = (const float*)d_in[4];
    const float* Wv = (const float*)d_in[5];
    const float* bv = (const float*)d_in[6];
    float* out = (float*)d_out;

    char* ws = (char*)d_ws;
    unsigned short* qsc   = (unsigned short*)ws;                 // 8 MB bf16 q*SC, [n][d]
    unsigned short* ksr   = (unsigned short*)(ws + 0x1000000);   // 8 MB bf16 K row-major
    unsigned short* vt2   = (unsigned short*)(ws + 0x2000000);   // 8 MB bf16 V^T frag-major
    unsigned short* wfrag = (unsigned short*)(ws + 0x3000000);   // 64 KB W frags

    wprep_kernel<<<dim3(4), dim3(256), 0, stream>>>(Wq, Wk, Wv, wfrag);
    qkv_kernel<<<dim3(1024), dim3(256), 0, stream>>>(
        x, wfrag, bq, bk, bv, qsc, ksr, vt2);
    attn_kernel<<<dim3(512), dim3(256), 0, stream>>>(
        qsc, ksr, vt2, out);
}